// Round 1
// baseline (896.935 us; speedup 1.0000x reference)
//
#include <hip/hip_runtime.h>

// GATReduce: a = sum_d(a1[n,d] + a2[n,k,d])  -> leaky_relu -> softmax over k
//            out[n,d] = sum_k e[n,k] * ft[n,k,d]
// N=30000, DEG=32, D=128, fp32 in / fp32 out. Memory-bound: ~1.01 GB traffic.

#define NN 30000
#define DEG 32
#define DD 128
#define NEG_SLOPE 0.01f

__global__ __launch_bounds__(256) void gat_reduce_kernel(
    const float* __restrict__ a1,
    const float* __restrict__ a2,
    const float* __restrict__ ft,
    float* __restrict__ out)
{
    const int n = blockIdx.x;
    const int t = threadIdx.x;
    const int h = t >> 5;   // half-wave id 0..7
    const int l = t & 31;   // lane within half-wave

    __shared__ float rowsum[33];          // [32]=sum(a1[n,:])
    __shared__ float ew[32];              // softmax weights
    __shared__ float partial[8][DD];      // per-half partial accumulators

    const float4* a2v = (const float4*)a2 + (size_t)n * (DEG * DD / 4);
    const float4* ftv = (const float4*)ft + (size_t)n * (DEG * DD / 4);
    const float4* a1v = (const float4*)a1 + (size_t)n * (DD / 4);

    // ---- Phase 1: row sums of a2[n,k,:] (32 rows) + a1[n,:] sum ----
    #pragma unroll
    for (int i = 0; i < 4; ++i) {
        const int k = h + 8 * i;                 // block reads rows 0..7, 8..15, ...
        float4 v = a2v[k * 32 + l];              // coalesced 16B/lane
        float s = v.x + v.y + v.z + v.w;
        #pragma unroll
        for (int m = 16; m >= 1; m >>= 1) s += __shfl_xor(s, m);  // stays in 32-lane half
        if (l == 0) rowsum[k] = s;
    }
    if (h == 0) {                                // half-wave 0 also sums a1[n,:]
        float4 v = a1v[l];
        float s = v.x + v.y + v.z + v.w;
        #pragma unroll
        for (int m = 16; m >= 1; m >>= 1) s += __shfl_xor(s, m);
        if (l == 0) rowsum[32] = s;
    }
    __syncthreads();

    // ---- Phase 2: leaky_relu + softmax over the 32 neighbors (lanes 0..31 of wave 0) ----
    if (t < 32) {
        float a = rowsum[t] + rowsum[32];
        float lr = a > 0.0f ? a : NEG_SLOPE * a;
        float m = lr;
        #pragma unroll
        for (int s = 16; s >= 1; s >>= 1) m = fmaxf(m, __shfl_xor(m, s));
        float p = __expf(lr - m);
        float sum = p;
        #pragma unroll
        for (int s = 16; s >= 1; s >>= 1) sum += __shfl_xor(sum, s);
        ew[t] = p / sum;
    }
    __syncthreads();

    // ---- Phase 3: out[n,:] = sum_k ew[k] * ft[n,k,:] ----
    float4 acc = make_float4(0.f, 0.f, 0.f, 0.f);
    #pragma unroll
    for (int i = 0; i < 4; ++i) {
        const int k = h + 8 * i;
        const float w = ew[k];                   // LDS broadcast
        float4 v = ftv[k * 32 + l];              // coalesced 16B/lane
        acc.x += w * v.x;
        acc.y += w * v.y;
        acc.z += w * v.z;
        acc.w += w * v.w;
    }
    *(float4*)&partial[h][4 * l] = acc;
    __syncthreads();

    if (t < DD) {
        float s = 0.f;
        #pragma unroll
        for (int j = 0; j < 8; ++j) s += partial[j][t];   // conflict-free: stride-128 rows
        out[(size_t)n * DD + t] = s;                       // coalesced 512B store
    }
}

extern "C" void kernel_launch(void* const* d_in, const int* in_sizes, int n_in,
                              void* d_out, int out_size, void* d_ws, size_t ws_size,
                              hipStream_t stream) {
    const float* a1 = (const float*)d_in[0];
    const float* a2 = (const float*)d_in[1];
    const float* ft = (const float*)d_in[2];
    float* out = (float*)d_out;
    gat_reduce_kernel<<<NN, 256, 0, stream>>>(a1, a2, ft, out);
}